// Round 9
// baseline (195.662 us; speedup 1.0000x reference)
//
#include <hip/hip_runtime.h>
#include <hip/hip_bf16.h>

// Problem constants (B=2, S=2048, E=1024, H=16, d=64)
#define BB 2
#define SS 2048
#define EE 1024
#define HH 16
#define DD 64

using bfrag  = __attribute__((ext_vector_type(8))) short;  // 8 bf16 (4 VGPRs)
using bfrag4 = __attribute__((ext_vector_type(4))) short;  // 4 bf16 (2 VGPRs)
using ffrag  = __attribute__((ext_vector_type(4))) float;  // 4 fp32 accum
using uint2v = __attribute__((ext_vector_type(2))) uint;

#define MFMA32(A, B, C) __builtin_amdgcn_mfma_f32_16x16x32_bf16(A, B, C, 0, 0, 0)
#define MFMA16(A, B, C) __builtin_amdgcn_mfma_f32_16x16x16bf16_1k(A, B, C, 0, 0, 0)

static __device__ __forceinline__ ushort f2bf(float f) {
  __hip_bfloat16 h = __float2bfloat16(f);
  return *reinterpret_cast<ushort*>(&h);
}

// Pack two fp32 -> two bf16 (round-half-up) in 3 VALU ops via v_perm_b32.
static __device__ __forceinline__ uint pack_bf2(float lo, float hi) {
  uint a = __float_as_uint(lo) + 0x8000u;
  uint b = __float_as_uint(hi) + 0x8000u;
  return __builtin_amdgcn_perm(b, a, 0x07060302u);
}

// Async global->LDS, 16 B per lane. LDS dest = wave-uniform base + lane*16.
static __device__ __forceinline__ void gl_lds16(const ushort* g, ushort* l) {
  __builtin_amdgcn_global_load_lds(
      (const __attribute__((address_space(1))) void*)g,
      (__attribute__((address_space(3))) void*)l, 16, 0, 0);
}

// -------------------------------------------------------------------------
// Fused prep: x fp32->bf16 cast (blocks 0..4095) + weight transpose+cast
// (blocks 4096..6271): wq -> wqkvT[0:1024), wo -> woT, wk -> wqkvT[1024:1088),
// wv -> wqkvT[1088:1152).
// -------------------------------------------------------------------------
__global__ __launch_bounds__(256) void prep(
    const float* __restrict__ x, const float* __restrict__ wq,
    const float* __restrict__ wk, const float* __restrict__ wv,
    const float* __restrict__ wo, ushort* __restrict__ xb,
    ushort* __restrict__ wqkvT, ushort* __restrict__ woT) {
  __shared__ float t[32][33];
  int id = blockIdx.x;
  if (id < 4096) {  // cast path: 4096*256*4 = 4M elements
    int i = id * 256 + threadIdx.x;
    float4 v = ((const float4*)x)[i];
    ushort4 u = { f2bf(v.x), f2bf(v.y), f2bf(v.z), f2bf(v.w) };
    ((ushort4*)xb)[i] = u;
    return;
  }
  id -= 4096;
  const float* src;
  ushort* dst;
  int N, bx, by;
  if (id < 1024)      { src = wq; dst = wqkvT;                      N = 1024; bx = id & 31;          by = id >> 5; }
  else if (id < 2048) { src = wo; dst = woT;                        N = 1024; bx = (id - 1024) & 31; by = (id - 1024) >> 5; }
  else if (id < 2112) { src = wk; dst = wqkvT + (size_t)1024 * 1024; N = 64;  bx = (id - 2048) & 1;  by = (id - 2048) >> 1; }
  else                { src = wv; dst = wqkvT + (size_t)1088 * 1024; N = 64;  bx = (id - 2112) & 1;  by = (id - 2112) >> 1; }
  const int k0 = by * 32, n0 = bx * 32;
  const int tx = threadIdx.x & 31, ty = threadIdx.x >> 5;  // 32x8
  #pragma unroll
  for (int i = 0; i < 32; i += 8)
    t[ty + i][tx] = src[(size_t)(k0 + ty + i) * N + n0 + tx];
  __syncthreads();
  #pragma unroll
  for (int i = 0; i < 32; i += 8)
    dst[(size_t)(n0 + ty + i) * 1024 + k0 + tx] = f2bf(t[tx][ty + i]);
}

// -------------------------------------------------------------------------
// bf16 MFMA GEMM v4 (m97-style): 128x128 tile, BK=32, 4 waves, wave tile
// 64x64 (4x4 MFMA) -> 16 MFMA per 8 ds_read_b128. Dbuf global_load_lds
// staging (32 KB LDS), one barrier/iter. XOR swizzle slot = ck^((row>>1)&3).
// blockIdx.x = M-TILE (32 of them): XCD k (= id%8) owns m-tiles = k mod 8,
// so per-XCD L2 working set = 4 A-panels (1 MB) + whole B (<=2.4 MB) < 4 MB.
// QKV=true: Bt = [wq|wk|wv]^T (N=1152). Epilogue per n-subtile:
//   col<1024 -> Qb (bf16, (acc+bq)*qscale); 1024..1088 -> Kb [4096x64];
//   1088..1152 -> VT [B][64][S] (transposed, vectorized b64 stores).
// QKV=false: fp32 out = acc + bias0 (O projection).
// -------------------------------------------------------------------------
template <bool QKV>
__global__ __launch_bounds__(256) void gemm_mfma4(
    const ushort* __restrict__ A, const ushort* __restrict__ Bt,
    const float* __restrict__ bias0, const float* __restrict__ bias1,
    const float* __restrict__ bias2, void* __restrict__ O1,
    ushort* __restrict__ Kb, ushort* __restrict__ VTb,
    int M, int N, int K, float qscale) {
  __shared__ __align__(16) ushort As[2][128 * 32];
  __shared__ __align__(16) ushort Bs[2][128 * 32];
  const int tid = threadIdx.x;
  const int lane = tid & 63;
  const int quad = lane >> 4;
  const int c = lane & 15;
  const int wv = tid >> 6;          // 0..3
  const int wm = (wv & 1) * 64;
  const int wn = (wv >> 1) * 64;
  const size_t m0 = (size_t)blockIdx.x * 128;   // m-tile = fast grid dim
  const size_t n0 = (size_t)blockIdx.y * 128;

  // staging: instr covers 16 rows x 4 swizzled 16B chunks; 2 A + 2 B per wave
  const int srow = lane >> 2;
  const int skc = (lane & 3) ^ ((lane >> 3) & 3);
  const int ia0 = wv * 2, ia1 = wv * 2 + 1;
  const int ra0 = ia0 * 16 + srow, ra1 = ia1 * 16 + srow;

  ffrag zero = {0.f, 0.f, 0.f, 0.f};
  ffrag acc[4][4];
  #pragma unroll
  for (int mt = 0; mt < 4; ++mt)
    #pragma unroll
    for (int nt = 0; nt < 4; ++nt) acc[mt][nt] = zero;

  const int NK = K >> 5;
  gl_lds16(&A[(m0 + ra0) * (size_t)K + skc * 8], &As[0][ia0 * 512]);
  gl_lds16(&A[(m0 + ra1) * (size_t)K + skc * 8], &As[0][ia1 * 512]);
  gl_lds16(&Bt[(n0 + ra0) * (size_t)K + skc * 8], &Bs[0][ia0 * 512]);
  gl_lds16(&Bt[(n0 + ra1) * (size_t)K + skc * 8], &Bs[0][ia1 * 512]);
  __syncthreads();

  for (int ki = 0; ki < NK; ++ki) {
    const int buf = ki & 1;
    if (ki + 1 < NK) {  // prefetch next tile; stays in flight through compute
      int k0 = (ki + 1) << 5;
      gl_lds16(&A[(m0 + ra0) * (size_t)K + k0 + skc * 8], &As[buf ^ 1][ia0 * 512]);
      gl_lds16(&A[(m0 + ra1) * (size_t)K + k0 + skc * 8], &As[buf ^ 1][ia1 * 512]);
      gl_lds16(&Bt[(n0 + ra0) * (size_t)K + k0 + skc * 8], &Bs[buf ^ 1][ia0 * 512]);
      gl_lds16(&Bt[(n0 + ra1) * (size_t)K + k0 + skc * 8], &Bs[buf ^ 1][ia1 * 512]);
    }
    bfrag af[4], bf[4];
    #pragma unroll
    for (int t = 0; t < 4; ++t) {
      int ra = wm + t * 16 + c;
      af[t] = *(const bfrag*)&As[buf][(ra * 4 + (quad ^ ((ra >> 1) & 3))) * 8];
      int rb = wn + t * 16 + c;
      bf[t] = *(const bfrag*)&Bs[buf][(rb * 4 + (quad ^ ((rb >> 1) & 3))) * 8];
    }
    #pragma unroll
    for (int mt = 0; mt < 4; ++mt)
      #pragma unroll
      for (int nt = 0; nt < 4; ++nt)
        acc[mt][nt] = MFMA32(af[mt], bf[nt], acc[mt][nt]);
    __syncthreads();
  }

  #pragma unroll
  for (int nt = 0; nt < 4; ++nt) {
    const int colb = (int)n0 + wn + nt * 16;  // multiple of 16
    if (QKV) {
      if (colb < 1024) {         // Q block (pre-scaled bf16)
        float bb = bias0[colb + c];
        ushort* dst = (ushort*)O1 + colb;
        #pragma unroll
        for (int mt = 0; mt < 4; ++mt)
          #pragma unroll
          for (int r = 0; r < 4; ++r) {
            size_t row = m0 + wm + mt * 16 + quad * 4 + r;
            dst[row * 1024 + c] = f2bf((acc[mt][nt][r] + bb) * qscale);
          }
      } else if (colb < 1088) {  // K block -> Kb [4096 x 64]
        float bb = bias1[colb - 1024 + c];
        ushort* dst = Kb + (colb - 1024);
        #pragma unroll
        for (int mt = 0; mt < 4; ++mt)
          #pragma unroll
          for (int r = 0; r < 4; ++r) {
            size_t row = m0 + wm + mt * 16 + quad * 4 + r;
            dst[row * 64 + c] = f2bf(acc[mt][nt][r] + bb);
          }
      } else {                   // V block -> VT [B][64][S] (transposed)
        int d = colb - 1088 + c;
        float bb = bias2[colb - 1088 + c];
        int bidx = (int)(m0 >> 11);
        ushort* dstv = VTb + ((size_t)(bidx * 64 + d)) * SS;
        #pragma unroll
        for (int mt = 0; mt < 4; ++mt) {
          int sb = (int)(m0 & 2047) + wm + mt * 16 + quad * 4;
          uint2v u;
          u.x = pack_bf2(acc[mt][nt][0] + bb, acc[mt][nt][1] + bb);
          u.y = pack_bf2(acc[mt][nt][2] + bb, acc[mt][nt][3] + bb);
          *(uint2v*)&dstv[sb] = u;
        }
      }
    } else {
      float bb = bias0[colb + c];
      float* dst = (float*)O1;
      #pragma unroll
      for (int mt = 0; mt < 4; ++mt)
        #pragma unroll
        for (int r = 0; r < 4; ++r) {
          size_t row = m0 + wm + mt * 16 + quad * 4 + r;
          dst[row * (size_t)N + colb + c] = acc[mt][nt][r] + bb;
        }
    }
  }
}

// -------------------------------------------------------------------------
// MQA attention v8 (unchanged from round 8). Block = 128 queries
// (4 waves x 32q), 512 blocks. Dbuf K/V LDS staging (32 KB; no P region).
// S^T = MFMA32(K, Q); exp2+pack makes the P fragment the B-operand of a
// K=16 MFMA directly from registers. O^T accum; lsum via MFMA16(ones, P).
// Output in the "faithful reshape bug" layout.
// -------------------------------------------------------------------------
__global__ __launch_bounds__(256) void mqa_attn8(
    const ushort* __restrict__ Q, const ushort* __restrict__ Kg,
    const ushort* __restrict__ VT, ushort* __restrict__ A2) {
  __shared__ __align__(16) ushort Kt[2][4096];  // 64 keys x 64 d (swizzled)
  __shared__ __align__(16) ushort Vt[2][4096];  // 64 d x 64 keys (swizzled)
  const int tid = threadIdx.x;
  const int lane = tid & 63;
  const int quad = lane >> 4;
  const int c = lane & 15;
  const int wv = tid >> 6;
  const int bid = blockIdx.x;     // [0, 512)
  const int b = bid >> 8;
  const int r = bid & 255;
  const int h = r >> 4;           // 16 blocks per head
  const int s0 = (r & 15) << 7;   // 128 queries per block

  const int srow = lane >> 3;            // row within 8-row slab
  const int sck = (lane & 7) ^ srow;     // swizzled chunk within row

  ffrag zero = {0.f, 0.f, 0.f, 0.f};
  bfrag4 ones4;
  #pragma unroll
  for (int i = 0; i < 4; ++i) ones4[i] = (short)16256;  // bf16 1.0

  bfrag aq[2][2];
  #pragma unroll
  for (int mt = 0; mt < 2; ++mt) {
    const ushort* qp =
        Q + ((size_t)(b * SS) + s0 + wv * 32 + mt * 16 + c) * EE + h * 64 + quad * 8;
    aq[mt][0] = *(const bfrag*)qp;
    aq[mt][1] = *(const bfrag*)(qp + 32);
  }

  ffrag o[2][4];   // O^T accum: [q-tile][d-tile]
  #pragma unroll
  for (int mt = 0; mt < 2; ++mt)
    #pragma unroll
    for (int nt = 0; nt < 4; ++nt) o[mt][nt] = zero;
  ffrag ls[2] = {zero, zero};

  const ushort* Kbase = Kg + (size_t)b * SS * 64;
  const ushort* Vbase = VT + (size_t)b * 64 * SS;
  const int i0 = wv * 2, i1 = wv * 2 + 1;
  const int r0 = i0 * 8 + srow, r1 = i1 * 8 + srow;

  gl_lds16(Kbase + (size_t)r0 * 64 + sck * 8, &Kt[0][i0 * 512]);
  gl_lds16(Kbase + (size_t)r1 * 64 + sck * 8, &Kt[0][i1 * 512]);
  gl_lds16(Vbase + (size_t)r0 * SS + sck * 8, &Vt[0][i0 * 512]);
  gl_lds16(Vbase + (size_t)r1 * SS + sck * 8, &Vt[0][i1 * 512]);
  __syncthreads();

  for (int it = 0; it < 32; ++it) {
    const int buf = it & 1;
    if (it + 1 < 32) {  // early-issue next K/V tile
      int kb = (it + 1) << 6;
      gl_lds16(Kbase + (size_t)(kb + r0) * 64 + sck * 8, &Kt[buf ^ 1][i0 * 512]);
      gl_lds16(Kbase + (size_t)(kb + r1) * 64 + sck * 8, &Kt[buf ^ 1][i1 * 512]);
      gl_lds16(Vbase + (size_t)r0 * SS + kb + sck * 8, &Vt[buf ^ 1][i0 * 512]);
      gl_lds16(Vbase + (size_t)r1 * SS + kb + sck * 8, &Vt[buf ^ 1][i1 * 512]);
    }

    #pragma unroll
    for (int kt = 0; kt < 4; ++kt) {
      const int key = kt * 16 + c;
      const int k7 = key & 7;
      bfrag kf0 = *(const bfrag*)&Kt[buf][(key * 8 + (quad ^ k7)) * 8];
      bfrag kf1 = *(const bfrag*)&Kt[buf][(key * 8 + ((quad + 4) ^ k7)) * 8];
      bfrag4 pb[2];
      #pragma unroll
      for (int mt = 0; mt < 2; ++mt) {
        ffrag st = MFMA32(kf0, aq[mt][0], zero);
        st = MFMA32(kf1, aq[mt][1], st);
        uint2v uu;
        uu.x = pack_bf2(__builtin_amdgcn_exp2f(st[0]),
                        __builtin_amdgcn_exp2f(st[1]));
        uu.y = pack_bf2(__builtin_amdgcn_exp2f(st[2]),
                        __builtin_amdgcn_exp2f(st[3]));
        pb[mt] = __builtin_bit_cast(bfrag4, uu);
      }
      const int ck = kt * 2 + (quad >> 1);
      const int wc = (quad & 1) * 4;
      #pragma unroll
      for (int nt = 0; nt < 4; ++nt) {
        int d = nt * 16 + c;
        bfrag4 vf = *(const bfrag4*)&Vt[buf][(d * 8 + (ck ^ (d & 7))) * 8 + wc];
        #pragma unroll
        for (int mt = 0; mt < 2; ++mt)
          o[mt][nt] = MFMA16(vf, pb[mt], o[mt][nt]);
      }
      #pragma unroll
      for (int mt = 0; mt < 2; ++mt)
        ls[mt] = MFMA16(ones4, pb[mt], ls[mt]);
    }
    __syncthreads();
  }

  #pragma unroll
  for (int mt = 0; mt < 2; ++mt) {
    const float inv = 1.f / ls[mt][0];
    const int sp = h * 128 + (s0 >> 4) + wv * 2 + mt;
    ushort* orow = A2 + ((size_t)b * SS + sp) * EE;
    #pragma unroll
    for (int nt = 0; nt < 4; ++nt) {
      uint2v u;
      u.x = pack_bf2(o[mt][nt][0] * inv, o[mt][nt][1] * inv);
      u.y = pack_bf2(o[mt][nt][2] * inv, o[mt][nt][3] * inv);
      *(uint2v*)&orow[c * 64 + nt * 16 + quad * 4] = u;
    }
  }
}

extern "C" void kernel_launch(void* const* d_in, const int* in_sizes, int n_in,
                              void* d_out, int out_size, void* d_ws, size_t ws_size,
                              hipStream_t stream) {
  const float* x  = (const float*)d_in[0];
  const float* wq = (const float*)d_in[1];
  const float* bq = (const float*)d_in[2];
  const float* wk = (const float*)d_in[3];
  const float* bk = (const float*)d_in[4];
  const float* wv = (const float*)d_in[5];
  const float* bv = (const float*)d_in[6];
  const float* wo = (const float*)d_in[7];
  const float* bo = (const float*)d_in[8];
  float* out = (float*)d_out;

  // Workspace layout (bytes)
  char* w = (char*)d_ws;
  ushort* xb     = (ushort*)w;  w += (size_t)4096 * 1024 * 2;  // x bf16
  ushort* wqkvT  = (ushort*)w;  w += (size_t)1152 * 1024 * 2;  // [wq|wk|wv]^T
  ushort* woT    = (ushort*)w;  w += (size_t)1024 * 1024 * 2;  // wo^T bf16
  ushort* Qb     = (ushort*)w;  w += (size_t)4096 * 1024 * 2;  // Q' (pre-scaled)
  ushort* Kb     = (ushort*)w;  w += (size_t)4096 * 64 * 2;    // K bf16 [4096x64]
  ushort* VTb    = (ushort*)w;  w += (size_t)BB * 64 * SS * 2; // V^T bf16
  ushort* A2     = (ushort*)w;  w += (size_t)4096 * 1024 * 2;  // attn (scrambled)

  // Prep: x cast + all weight transposes in one launch
  prep<<<6272, 256, 0, stream>>>(x, wq, wk, wv, wo, xb, wqkvT, woT);

  // Fused QKV projection (V written transposed). Q' scaled by 0.125*log2(e).
  // Grid: x = m-tile (XCD-partitioned A reuse), y = n-tile.
  const float qscale = 0.18033688011112042f;  // log2(e)/8
  gemm_mfma4<true><<<dim3(32, 9), 256, 0, stream>>>(
      xb, wqkvT, bq, bk, bv, Qb, Kb, VTb, 4096, 1152, 1024, qscale);

  // Attention (P-in-registers via K=16 MFMA)
  mqa_attn8<<<512, 256, 0, stream>>>(Qb, Kb, VTb, A2);

  // Output projection (fp32 out + bias)
  gemm_mfma4<false><<<dim3(32, 8), 256, 0, stream>>>(
      A2, woT, bo, nullptr, nullptr, out, nullptr, nullptr, 4096, 1024, 1024, 1.0f);
}

// Round 10
// 193.845 us; speedup vs baseline: 1.0094x; 1.0094x over previous
//
#include <hip/hip_runtime.h>
#include <hip/hip_bf16.h>

// Problem constants (B=2, S=2048, E=1024, H=16, d=64)
#define BB 2
#define SS 2048
#define EE 1024
#define HH 16
#define DD 64

using bfrag  = __attribute__((ext_vector_type(8))) short;  // 8 bf16 (4 VGPRs)
using bfrag4 = __attribute__((ext_vector_type(4))) short;  // 4 bf16 (2 VGPRs)
using ffrag  = __attribute__((ext_vector_type(4))) float;  // 4 fp32 accum
using uint2v = __attribute__((ext_vector_type(2))) uint;

#define MFMA32(A, B, C) __builtin_amdgcn_mfma_f32_16x16x32_bf16(A, B, C, 0, 0, 0)
#define MFMA16(A, B, C) __builtin_amdgcn_mfma_f32_16x16x16bf16_1k(A, B, C, 0, 0, 0)

static __device__ __forceinline__ ushort f2bf(float f) {
  __hip_bfloat16 h = __float2bfloat16(f);
  return *reinterpret_cast<ushort*>(&h);
}

// Pack two fp32 -> two bf16 (round-half-up) in 3 VALU ops via v_perm_b32.
static __device__ __forceinline__ uint pack_bf2(float lo, float hi) {
  uint a = __float_as_uint(lo) + 0x8000u;
  uint b = __float_as_uint(hi) + 0x8000u;
  return __builtin_amdgcn_perm(b, a, 0x07060302u);
}

// Async global->LDS, 16 B per lane. LDS dest = wave-uniform base + lane*16.
static __device__ __forceinline__ void gl_lds16(const ushort* g, ushort* l) {
  __builtin_amdgcn_global_load_lds(
      (const __attribute__((address_space(1))) void*)g,
      (__attribute__((address_space(3))) void*)l, 16, 0, 0);
}

// -------------------------------------------------------------------------
// Fused prep: x fp32->bf16 cast (blocks 0..4095) + weight transpose+cast
// (blocks 4096..6271): wq -> wqkvT[0:1024), wo -> woT, wk -> wqkvT[1024:1088),
// wv -> wqkvT[1088:1152).
// -------------------------------------------------------------------------
__global__ __launch_bounds__(256) void prep(
    const float* __restrict__ x, const float* __restrict__ wq,
    const float* __restrict__ wk, const float* __restrict__ wv,
    const float* __restrict__ wo, ushort* __restrict__ xb,
    ushort* __restrict__ wqkvT, ushort* __restrict__ woT) {
  __shared__ float t[32][33];
  int id = blockIdx.x;
  if (id < 4096) {  // cast path: 4096*256*4 = 4M elements
    int i = id * 256 + threadIdx.x;
    float4 v = ((const float4*)x)[i];
    ushort4 u = { f2bf(v.x), f2bf(v.y), f2bf(v.z), f2bf(v.w) };
    ((ushort4*)xb)[i] = u;
    return;
  }
  id -= 4096;
  const float* src;
  ushort* dst;
  int N, bx, by;
  if (id < 1024)      { src = wq; dst = wqkvT;                      N = 1024; bx = id & 31;          by = id >> 5; }
  else if (id < 2048) { src = wo; dst = woT;                        N = 1024; bx = (id - 1024) & 31; by = (id - 1024) >> 5; }
  else if (id < 2112) { src = wk; dst = wqkvT + (size_t)1024 * 1024; N = 64;  bx = (id - 2048) & 1;  by = (id - 2048) >> 1; }
  else                { src = wv; dst = wqkvT + (size_t)1088 * 1024; N = 64;  bx = (id - 2112) & 1;  by = (id - 2112) >> 1; }
  const int k0 = by * 32, n0 = bx * 32;
  const int tx = threadIdx.x & 31, ty = threadIdx.x >> 5;  // 32x8
  #pragma unroll
  for (int i = 0; i < 32; i += 8)
    t[ty + i][tx] = src[(size_t)(k0 + ty + i) * N + n0 + tx];
  __syncthreads();
  #pragma unroll
  for (int i = 0; i < 32; i += 8)
    dst[(size_t)(n0 + ty + i) * 1024 + k0 + tx] = f2bf(t[tx][ty + i]);
}

// -------------------------------------------------------------------------
// bf16 MFMA GEMM v5: 128(M)x64(N) tile, BK=32, TWO waves (128 thr), wave
// tile 64x64 (4x4 MFMA -> 16 MFMA per 8 ds_read_b128, m97 ratio). 24 KB
// LDS dbuf -> many small blocks co-resident (grid 576/512 = ~2.25/CU);
// cross-block overlap hides the per-iter barrier drain that 1-block/CU
// 128x128 tiling exposed (r9 regression). Flat grid: m-tile = id&31 ->
// XCD k owns m = k mod 8 (A panel 1 MB + B <= 2.25 MB fits 4 MB L2).
// QKV=true: Bt = [wq|wk|wv]^T (N=1152). Epilogue per n-subtile:
//   col<1024 -> Qb (bf16, (acc+bq)*qscale); 1024..1088 -> Kb [4096x64];
//   1088..1152 -> VT [B][64][S] (transposed, b64 stores).
// QKV=false: fp32 out = acc + bias0 (O projection).
// -------------------------------------------------------------------------
template <bool QKV>
__global__ __launch_bounds__(128) void gemm_mfma5(
    const ushort* __restrict__ A, const ushort* __restrict__ Bt,
    const float* __restrict__ bias0, const float* __restrict__ bias1,
    const float* __restrict__ bias2, void* __restrict__ O1,
    ushort* __restrict__ Kb, ushort* __restrict__ VTb,
    int M, int N, int K, float qscale) {
  __shared__ __align__(16) ushort As[2][128 * 32];
  __shared__ __align__(16) ushort Bs[2][64 * 32];
  const int tid = threadIdx.x;
  const int lane = tid & 63;
  const int quad = lane >> 4;
  const int c = lane & 15;
  const int wv = tid >> 6;          // 0..1
  const int wm = wv * 64;
  const int id = blockIdx.x;
  const size_t m0 = (size_t)(id & 31) * 128;   // m-tile fast -> XCD partition
  const size_t n0 = (size_t)(id >> 5) * 64;

  // staging: each 1KB instr covers 16 rows x 4 swizzled 16B chunks
  const int srow = lane >> 2;
  const int skc = (lane & 3) ^ ((lane >> 3) & 3);

  ffrag zero = {0.f, 0.f, 0.f, 0.f};
  ffrag acc[4][4];
  #pragma unroll
  for (int mt = 0; mt < 4; ++mt)
    #pragma unroll
    for (int nt = 0; nt < 4; ++nt) acc[mt][nt] = zero;

  const int NK = K >> 5;
  // prologue: stage tile 0 into buf 0 (A: 8 instrs, B: 4; split by wave)
  #pragma unroll
  for (int i = 0; i < 4; ++i) {
    int ia = wv * 4 + i;
    gl_lds16(&A[(m0 + ia * 16 + srow) * (size_t)K + skc * 8], &As[0][ia * 512]);
  }
  #pragma unroll
  for (int i = 0; i < 2; ++i) {
    int ib = wv * 2 + i;
    gl_lds16(&Bt[(n0 + ib * 16 + srow) * (size_t)K + skc * 8], &Bs[0][ib * 512]);
  }
  __syncthreads();

  for (int ki = 0; ki < NK; ++ki) {
    const int buf = ki & 1;
    if (ki + 1 < NK) {  // prefetch next tile; stays in flight through MFMA
      int k0 = (ki + 1) << 5;
      #pragma unroll
      for (int i = 0; i < 4; ++i) {
        int ia = wv * 4 + i;
        gl_lds16(&A[(m0 + ia * 16 + srow) * (size_t)K + k0 + skc * 8],
                 &As[buf ^ 1][ia * 512]);
      }
      #pragma unroll
      for (int i = 0; i < 2; ++i) {
        int ib = wv * 2 + i;
        gl_lds16(&Bt[(n0 + ib * 16 + srow) * (size_t)K + k0 + skc * 8],
                 &Bs[buf ^ 1][ib * 512]);
      }
    }
    bfrag af[4], bf[4];
    #pragma unroll
    for (int t = 0; t < 4; ++t) {
      int ra = wm + t * 16 + c;
      af[t] = *(const bfrag*)&As[buf][(ra * 4 + (quad ^ ((ra >> 1) & 3))) * 8];
      int rb = t * 16 + c;
      bf[t] = *(const bfrag*)&Bs[buf][(rb * 4 + (quad ^ ((rb >> 1) & 3))) * 8];
    }
    #pragma unroll
    for (int mt = 0; mt < 4; ++mt)
      #pragma unroll
      for (int nt = 0; nt < 4; ++nt)
        acc[mt][nt] = MFMA32(af[mt], bf[nt], acc[mt][nt]);
    __syncthreads();
  }

  #pragma unroll
  for (int nt = 0; nt < 4; ++nt) {
    const int colb = (int)n0 + nt * 16;  // multiple of 16
    if (QKV) {
      if (colb < 1024) {         // Q block (pre-scaled bf16)
        float bb = bias0[colb + c];
        ushort* dst = (ushort*)O1 + colb;
        #pragma unroll
        for (int mt = 0; mt < 4; ++mt)
          #pragma unroll
          for (int r = 0; r < 4; ++r) {
            size_t row = m0 + wm + mt * 16 + quad * 4 + r;
            dst[row * 1024 + c] = f2bf((acc[mt][nt][r] + bb) * qscale);
          }
      } else if (colb < 1088) {  // K block -> Kb [4096 x 64]
        float bb = bias1[colb - 1024 + c];
        ushort* dst = Kb + (colb - 1024);
        #pragma unroll
        for (int mt = 0; mt < 4; ++mt)
          #pragma unroll
          for (int r = 0; r < 4; ++r) {
            size_t row = m0 + wm + mt * 16 + quad * 4 + r;
            dst[row * 64 + c] = f2bf(acc[mt][nt][r] + bb);
          }
      } else {                   // V block -> VT [B][64][S] (transposed)
        int d = colb - 1088 + c;
        float bb = bias2[colb - 1088 + c];
        int bidx = (int)(m0 >> 11);
        ushort* dstv = VTb + ((size_t)(bidx * 64 + d)) * SS;
        #pragma unroll
        for (int mt = 0; mt < 4; ++mt) {
          int sb = (int)(m0 & 2047) + wm + mt * 16 + quad * 4;
          uint2v u;
          u.x = pack_bf2(acc[mt][nt][0] + bb, acc[mt][nt][1] + bb);
          u.y = pack_bf2(acc[mt][nt][2] + bb, acc[mt][nt][3] + bb);
          *(uint2v*)&dstv[sb] = u;
        }
      }
    } else {
      float bb = bias0[colb + c];
      float* dst = (float*)O1;
      #pragma unroll
      for (int mt = 0; mt < 4; ++mt)
        #pragma unroll
        for (int r = 0; r < 4; ++r) {
          size_t row = m0 + wm + mt * 16 + quad * 4 + r;
          dst[row * (size_t)N + colb + c] = acc[mt][nt][r] + bb;
        }
    }
  }
}

// -------------------------------------------------------------------------
// MQA attention v8 (unchanged). Block = 128 queries (4 waves x 32q), 512
// blocks. Dbuf K/V LDS staging (32 KB; no P region). S^T = MFMA32(K, Q);
// exp2+pack makes the P fragment the B-operand of a K=16 MFMA directly
// from registers. O^T accum; lsum via MFMA16(ones, P).
// Output in the "faithful reshape bug" layout.
// -------------------------------------------------------------------------
__global__ __launch_bounds__(256) void mqa_attn8(
    const ushort* __restrict__ Q, const ushort* __restrict__ Kg,
    const ushort* __restrict__ VT, ushort* __restrict__ A2) {
  __shared__ __align__(16) ushort Kt[2][4096];  // 64 keys x 64 d (swizzled)
  __shared__ __align__(16) ushort Vt[2][4096];  // 64 d x 64 keys (swizzled)
  const int tid = threadIdx.x;
  const int lane = tid & 63;
  const int quad = lane >> 4;
  const int c = lane & 15;
  const int wv = tid >> 6;
  const int bid = blockIdx.x;     // [0, 512)
  const int b = bid >> 8;
  const int r = bid & 255;
  const int h = r >> 4;           // 16 blocks per head
  const int s0 = (r & 15) << 7;   // 128 queries per block

  const int srow = lane >> 3;            // row within 8-row slab
  const int sck = (lane & 7) ^ srow;     // swizzled chunk within row

  ffrag zero = {0.f, 0.f, 0.f, 0.f};
  bfrag4 ones4;
  #pragma unroll
  for (int i = 0; i < 4; ++i) ones4[i] = (short)16256;  // bf16 1.0

  bfrag aq[2][2];
  #pragma unroll
  for (int mt = 0; mt < 2; ++mt) {
    const ushort* qp =
        Q + ((size_t)(b * SS) + s0 + wv * 32 + mt * 16 + c) * EE + h * 64 + quad * 8;
    aq[mt][0] = *(const bfrag*)qp;
    aq[mt][1] = *(const bfrag*)(qp + 32);
  }

  ffrag o[2][4];   // O^T accum: [q-tile][d-tile]
  #pragma unroll
  for (int mt = 0; mt < 2; ++mt)
    #pragma unroll
    for (int nt = 0; nt < 4; ++nt) o[mt][nt] = zero;
  ffrag ls[2] = {zero, zero};

  const ushort* Kbase = Kg + (size_t)b * SS * 64;
  const ushort* Vbase = VT + (size_t)b * 64 * SS;
  const int i0 = wv * 2, i1 = wv * 2 + 1;
  const int r0 = i0 * 8 + srow, r1 = i1 * 8 + srow;

  gl_lds16(Kbase + (size_t)r0 * 64 + sck * 8, &Kt[0][i0 * 512]);
  gl_lds16(Kbase + (size_t)r1 * 64 + sck * 8, &Kt[0][i1 * 512]);
  gl_lds16(Vbase + (size_t)r0 * SS + sck * 8, &Vt[0][i0 * 512]);
  gl_lds16(Vbase + (size_t)r1 * SS + sck * 8, &Vt[0][i1 * 512]);
  __syncthreads();

  for (int it = 0; it < 32; ++it) {
    const int buf = it & 1;
    if (it + 1 < 32) {  // early-issue next K/V tile
      int kb = (it + 1) << 6;
      gl_lds16(Kbase + (size_t)(kb + r0) * 64 + sck * 8, &Kt[buf ^ 1][i0 * 512]);
      gl_lds16(Kbase + (size_t)(kb + r1) * 64 + sck * 8, &Kt[buf ^ 1][i1 * 512]);
      gl_lds16(Vbase + (size_t)r0 * SS + kb + sck * 8, &Vt[buf ^ 1][i0 * 512]);
      gl_lds16(Vbase + (size_t)r1 * SS + kb + sck * 8, &Vt[buf ^ 1][i1 * 512]);
    }

    #pragma unroll
    for (int kt = 0; kt < 4; ++kt) {
      const int key = kt * 16 + c;
      const int k7 = key & 7;
      bfrag kf0 = *(const bfrag*)&Kt[buf][(key * 8 + (quad ^ k7)) * 8];
      bfrag kf1 = *(const bfrag*)&Kt[buf][(key * 8 + ((quad + 4) ^ k7)) * 8];
      bfrag4 pb[2];
      #pragma unroll
      for (int mt = 0; mt < 2; ++mt) {
        ffrag st = MFMA32(kf0, aq[mt][0], zero);
        st = MFMA32(kf1, aq[mt][1], st);
        uint2v uu;
        uu.x = pack_bf2(__builtin_amdgcn_exp2f(st[0]),
                        __builtin_amdgcn_exp2f(st[1]));
        uu.y = pack_bf2(__builtin_amdgcn_exp2f(st[2]),
                        __builtin_amdgcn_exp2f(st[3]));
        pb[mt] = __builtin_bit_cast(bfrag4, uu);
      }
      const int ck = kt * 2 + (quad >> 1);
      const int wc = (quad & 1) * 4;
      #pragma unroll
      for (int nt = 0; nt < 4; ++nt) {
        int d = nt * 16 + c;
        bfrag4 vf = *(const bfrag4*)&Vt[buf][(d * 8 + (ck ^ (d & 7))) * 8 + wc];
        #pragma unroll
        for (int mt = 0; mt < 2; ++mt)
          o[mt][nt] = MFMA16(vf, pb[mt], o[mt][nt]);
      }
      #pragma unroll
      for (int mt = 0; mt < 2; ++mt)
        ls[mt] = MFMA16(ones4, pb[mt], ls[mt]);
    }
    __syncthreads();
  }

  #pragma unroll
  for (int mt = 0; mt < 2; ++mt) {
    const float inv = 1.f / ls[mt][0];
    const int sp = h * 128 + (s0 >> 4) + wv * 2 + mt;
    ushort* orow = A2 + ((size_t)b * SS + sp) * EE;
    #pragma unroll
    for (int nt = 0; nt < 4; ++nt) {
      uint2v u;
      u.x = pack_bf2(o[mt][nt][0] * inv, o[mt][nt][1] * inv);
      u.y = pack_bf2(o[mt][nt][2] * inv, o[mt][nt][3] * inv);
      *(uint2v*)&orow[c * 64 + nt * 16 + quad * 4] = u;
    }
  }
}

extern "C" void kernel_launch(void* const* d_in, const int* in_sizes, int n_in,
                              void* d_out, int out_size, void* d_ws, size_t ws_size,
                              hipStream_t stream) {
  const float* x  = (const float*)d_in[0];
  const float* wq = (const float*)d_in[1];
  const float* bq = (const float*)d_in[2];
  const float* wk = (const float*)d_in[3];
  const float* bk = (const float*)d_in[4];
  const float* wv = (const float*)d_in[5];
  const float* bv = (const float*)d_in[6];
  const float* wo = (const float*)d_in[7];
  const float* bo = (const float*)d_in[8];
  float* out = (float*)d_out;

  // Workspace layout (bytes)
  char* w = (char*)d_ws;
  ushort* xb     = (ushort*)w;  w += (size_t)4096 * 1024 * 2;  // x bf16
  ushort* wqkvT  = (ushort*)w;  w += (size_t)1152 * 1024 * 2;  // [wq|wk|wv]^T
  ushort* woT    = (ushort*)w;  w += (size_t)1024 * 1024 * 2;  // wo^T bf16
  ushort* Qb     = (ushort*)w;  w += (size_t)4096 * 1024 * 2;  // Q' (pre-scaled)
  ushort* Kb     = (ushort*)w;  w += (size_t)4096 * 64 * 2;    // K bf16 [4096x64]
  ushort* VTb    = (ushort*)w;  w += (size_t)BB * 64 * SS * 2; // V^T bf16
  ushort* A2     = (ushort*)w;  w += (size_t)4096 * 1024 * 2;  // attn (scrambled)

  // Prep: x cast + all weight transposes in one launch
  prep<<<6272, 256, 0, stream>>>(x, wq, wk, wv, wo, xb, wqkvT, woT);

  // Fused QKV projection (V written transposed). Q' scaled by 0.125*log2(e).
  // 2-wave blocks, flat grid 32 m-tiles x 18 n-tiles = 576 blocks.
  const float qscale = 0.18033688011112042f;  // log2(e)/8
  gemm_mfma5<true><<<32 * 18, 128, 0, stream>>>(
      xb, wqkvT, bq, bk, bv, Qb, Kb, VTb, 4096, 1152, 1024, qscale);

  // Attention (P-in-registers via K=16 MFMA)
  mqa_attn8<<<512, 256, 0, stream>>>(Qb, Kb, VTb, A2);

  // Output projection (fp32 out + bias): 32 x 16 = 512 blocks
  gemm_mfma5<false><<<32 * 16, 128, 0, stream>>>(
      A2, woT, bo, nullptr, nullptr, out, nullptr, nullptr, 4096, 1024, 1024, 1.0f);
}